// Round 2
// baseline (244.064 us; speedup 1.0000x reference)
//
#include <hip/hip_runtime.h>
#include <stdint.h>

// Fused 2-layer LSTM (B=32768, T=64, F=8, H=16) + FC(16->512,relu) + FC(512->32)
// Strategy: one wave = 16 batch elements. bf16 hi/lo split MFMA (16x16x32) with
// fp32 accumulation -> ~1e-4 accuracy vs fp32 reference. Recurrent h repacked
// into A-fragments via per-wave LDS scratch (wave-internal, lgkmcnt fences only,
// no barriers). VALU-bound by gate activations per roofline estimate.

#define NT 64
#define NF 8

typedef __attribute__((ext_vector_type(8))) short bf16x8;
typedef __attribute__((ext_vector_type(4))) float f32x4;

#define MFMA16 __builtin_amdgcn_mfma_f32_16x16x32_bf16

static __device__ __forceinline__ short f2bf(float f) {
  uint32_t u = __float_as_uint(f);
  u += 0x7FFFu + ((u >> 16) & 1u);          // RTNE to bf16
  return (short)(u >> 16);
}
static __device__ __forceinline__ float bf2f(short s) {
  return __uint_as_float(((uint32_t)(uint16_t)s) << 16);
}
static __device__ __forceinline__ void split_hl(float f, short& hi, short& lo) {
  short h = f2bf(f);
  hi = h;
  lo = f2bf(f - bf2f(h));                    // exact residual, re-rounded
}
static __device__ __forceinline__ float sigmoidf_(float v) {
  return __builtin_amdgcn_rcpf(1.0f + __expf(-v));
}
// Wave-internal LDS write->read fence. sched_barrier(0) per guide rule #18:
// keep the machine scheduler from migrating LDS ops across the inline asm.
static __device__ __forceinline__ void lds_fence() {
  asm volatile("s_waitcnt lgkmcnt(0)" ::: "memory");
  __builtin_amdgcn_sched_barrier(0);
}

__global__ __launch_bounds__(256, 2) void lstm_fused(
    const float* __restrict__ x,
    const float* __restrict__ W1, const float* __restrict__ U1, const float* __restrict__ b1,
    const float* __restrict__ W2, const float* __restrict__ U2, const float* __restrict__ b2,
    const float* __restrict__ Wfc1, const float* __restrict__ bfc1,
    const float* __restrict__ Wfc2, const float* __restrict__ bfc2,
    float* __restrict__ out)
{
  const int tid  = threadIdx.x;
  const int lane = tid & 63;
  const int wv   = tid >> 6;
  const int col  = lane & 15;   // B-frag col / A-frag row / C-frag col
  const int g    = lane >> 4;   // K-group (slots 8g..8g+7)
  const int ho   = (g & 1) * 8; // column offset inside a 16-wide half
  const int base = (blockIdx.x * 4 + wv) * 16;

  // per-wave LDS: h-scratch [16 rows][24 shorts] x4 arrays, fc chunk [16][40] x2
  __shared__ __align__(16) short lds_all[4][1536 + 1280];
  short* const s1_hi = &lds_all[wv][0];
  short* const s1_lo = s1_hi + 384;
  short* const s2_hi = s1_hi + 768;
  short* const s2_lo = s1_hi + 1152;
  short* const c_hi  = s1_hi + 1536;
  short* const c_lo  = s1_hi + 1536 + 640;

  for (int i = lane; i < 1536; i += 64) s1_hi[i] = 0;   // h,c start at 0
  lds_fence();

  // ---- static B-fragments (weights), hi/lo split, built once per lane ----
  // LSTM1: B1a = [W1h; W1h; U1h] (K rows 0-7,8-15,16-31), B2a = [W1l; 0; U1l]
  // LSTM2: B1b = [W2h; U2h], B2b = [W2l; U2l]
  bf16x8 B1a[4], B2a[4], B1b[4], B2b[4];
#pragma unroll
  for (int n = 0; n < 4; ++n) {
    const int c = 16 * n + col;
#pragma unroll
    for (int j = 0; j < 8; ++j) {
      const int k = 8 * g + j;
      short h, l;
      if (k < 8)       { split_hl(W1[k * 64 + c], h, l);        B1a[n][j] = h; B2a[n][j] = l; }
      else if (k < 16) { split_hl(W1[(k - 8) * 64 + c], h, l);  B1a[n][j] = h; B2a[n][j] = 0; }
      else             { split_hl(U1[(k - 16) * 64 + c], h, l); B1a[n][j] = h; B2a[n][j] = l; }
      short h2, l2;
      if (k < 16) split_hl(W2[k * 64 + c], h2, l2);
      else        split_hl(U2[(k - 16) * 64 + c], h2, l2);
      B1b[n][j] = h2; B2b[n][j] = l2;
    }
  }

  float bias1[4], bias2[4];
#pragma unroll
  for (int n = 0; n < 4; ++n) { bias1[n] = b1[16 * n + col]; bias2[n] = b2[16 * n + col]; }

  f32x4 c1 = {0.f, 0.f, 0.f, 0.f};
  f32x4 c2 = {0.f, 0.f, 0.f, 0.f};

  const float* xrow = x + (size_t)(base + col) * (NT * NF);
  const short* const l2ph = (g < 2) ? s1_hi : s2_hi;   // LSTM2 A = [h1 | h2_prev]
  const short* const l2pl = (g < 2) ? s1_lo : s2_lo;

  for (int t = 0; t < NT; ++t) {
    // ===== LSTM1: z = [xh|xl|hh]@B1a + [xh|xl|hh]@B2a + [0|0|hl]@B1a + b1
    //            = (xh+xl)@W1h + xh@W1l + (hh+hl)@U1h + hh@U1l + b1
    f32x4 xa = *(const f32x4*)(xrow + t * NF);
    f32x4 xb = *(const f32x4*)(xrow + t * NF + 4);
    bf16x8 xh8, xl8;
#pragma unroll
    for (int j = 0; j < 4; ++j) {
      short h, l;
      split_hl(xa[j], h, l); xh8[j] = h;     xl8[j] = l;
      split_hl(xb[j], h, l); xh8[4 + j] = h; xl8[4 + j] = l;
    }
    bf16x8 hh = *(const bf16x8*)(s1_hi + col * 24 + ho);
    bf16x8 hl = *(const bf16x8*)(s1_lo + col * 24 + ho);
    bf16x8 A1, A3;
#pragma unroll
    for (int j = 0; j < 8; ++j) {
      A1[j] = (g == 0) ? xh8[j] : ((g == 1) ? xl8[j] : hh[j]);
      A3[j] = (g < 2) ? (short)0 : hl[j];
    }
    f32x4 z[4];
#pragma unroll
    for (int n = 0; n < 4; ++n) {
      f32x4 zi = {bias1[n], bias1[n], bias1[n], bias1[n]};
      zi = MFMA16(A1, B1a[n], zi, 0, 0, 0);
      zi = MFMA16(A1, B2a[n], zi, 0, 0, 0);
      zi = MFMA16(A3, B1a[n], zi, 0, 0, 0);
      z[n] = zi;
    }
    f32x4 h1v;
#pragma unroll
    for (int r = 0; r < 4; ++r) {
      float ig = sigmoidf_(z[0][r]);
      float fg = sigmoidf_(z[1][r]);
      float gg = fmaxf(z[2][r], 0.f);
      float og = sigmoidf_(z[3][r]);
      float cc = fg * c1[r] + ig * gg;
      c1[r] = cc;
      h1v[r] = og * fmaxf(cc, 0.f);
    }
#pragma unroll
    for (int r = 0; r < 4; ++r) {
      short h, l; split_hl(h1v[r], h, l);
      s1_hi[(4 * g + r) * 24 + col] = h;
      s1_lo[(4 * g + r) * 24 + col] = l;
    }
    lds_fence();

    // ===== LSTM2: z = [h1h|h2h]@B1b + [h1h|h2h]@B2b + [h1l|h2l]@B1b + b2
    bf16x8 A1c = *(const bf16x8*)(l2ph + col * 24 + ho);
    bf16x8 A3c = *(const bf16x8*)(l2pl + col * 24 + ho);
    f32x4 y[4];
#pragma unroll
    for (int n = 0; n < 4; ++n) {
      f32x4 yi = {bias2[n], bias2[n], bias2[n], bias2[n]};
      yi = MFMA16(A1c, B1b[n], yi, 0, 0, 0);
      yi = MFMA16(A1c, B2b[n], yi, 0, 0, 0);
      yi = MFMA16(A3c, B1b[n], yi, 0, 0, 0);
      y[n] = yi;
    }
    f32x4 h2v;
#pragma unroll
    for (int r = 0; r < 4; ++r) {
      float ig = sigmoidf_(y[0][r]);
      float fg = sigmoidf_(y[1][r]);
      float gg = fmaxf(y[2][r], 0.f);
      float og = sigmoidf_(y[3][r]);
      float cc = fg * c2[r] + ig * gg;
      c2[r] = cc;
      h2v[r] = og * fmaxf(cc, 0.f);
    }
#pragma unroll
    for (int r = 0; r < 4; ++r) {
      short h, l; split_hl(h2v[r], h, l);
      s2_hi[(4 * g + r) * 24 + col] = h;
      s2_lo[(4 * g + r) * 24 + col] = l;
    }
    lds_fence();
  }

  // ================= FC head =================
  // A_fc = [h2h(16) | h2l(16)]
  const short* pf = (g < 2) ? s2_hi : s2_lo;
  bf16x8 Afc = *(const bf16x8*)(pf + col * 24 + ho);

  f32x4 acc2[2];
#pragma unroll
  for (int nn = 0; nn < 2; ++nn) {
    float bb = bfc2[16 * nn + col];
    f32x4 a = {bb, bb, bb, bb};
    acc2[nn] = a;
  }

  for (int kc = 0; kc < 16; ++kc) {
    // FC1 tiles n = 2kc, 2kc+1:  y1 = relu((h2h+h2l)@(Wh+Wl) + b)
#pragma unroll
    for (int s = 0; s < 2; ++s) {
      const int c = 16 * (2 * kc + s) + col;
      bf16x8 Bh, Bl;
#pragma unroll
      for (int j = 0; j < 8; ++j) {
        short h, l;
        split_hl(Wfc1[((8 * g + j) & 15) * 512 + c], h, l);
        Bh[j] = h; Bl[j] = l;
      }
      float bb = bfc1[c];
      f32x4 acc = {bb, bb, bb, bb};
      acc = MFMA16(Afc, Bh, acc, 0, 0, 0);   // [h2h|h2l]@[Wh;Wh]
      acc = MFMA16(Afc, Bl, acc, 0, 0, 0);   // [h2h|h2l]@[Wl;Wl]
#pragma unroll
      for (int r = 0; r < 4; ++r) {
        short h, l;
        split_hl(fmaxf(acc[r], 0.f), h, l);
        c_hi[(4 * g + r) * 40 + 16 * s + col] = h;
        c_lo[(4 * g + r) * 40 + 16 * s + col] = l;
      }
    }
    lds_fence();
    // FC2 over this K=32 chunk
    bf16x8 Ah = *(const bf16x8*)(c_hi + col * 40 + 8 * g);
    bf16x8 Al = *(const bf16x8*)(c_lo + col * 40 + 8 * g);
#pragma unroll
    for (int nn = 0; nn < 2; ++nn) {
      bf16x8 Bh, Bl;
#pragma unroll
      for (int j = 0; j < 8; ++j) {
        short h, l;
        split_hl(Wfc2[(size_t)(32 * kc + 8 * g + j) * 32 + 16 * nn + col], h, l);
        Bh[j] = h; Bl[j] = l;
      }
      acc2[nn] = MFMA16(Ah, Bh, acc2[nn], 0, 0, 0);
      acc2[nn] = MFMA16(Al, Bh, acc2[nn], 0, 0, 0);
      acc2[nn] = MFMA16(Ah, Bl, acc2[nn], 0, 0, 0);
    }
    lds_fence();   // WAR: next chunk overwrites c_hi/c_lo
  }

#pragma unroll
  for (int nn = 0; nn < 2; ++nn)
#pragma unroll
    for (int r = 0; r < 4; ++r)
      out[(size_t)(base + 4 * g + r) * 32 + 16 * nn + col] = acc2[nn][r];
}

extern "C" void kernel_launch(void* const* d_in, const int* in_sizes, int n_in,
                              void* d_out, int out_size, void* d_ws, size_t ws_size,
                              hipStream_t stream) {
  const float* x    = (const float*)d_in[0];
  const float* W1   = (const float*)d_in[1];
  const float* U1   = (const float*)d_in[2];
  const float* b1   = (const float*)d_in[3];
  const float* W2   = (const float*)d_in[4];
  const float* U2   = (const float*)d_in[5];
  const float* b2   = (const float*)d_in[6];
  const float* Wfc1 = (const float*)d_in[7];
  const float* bfc1 = (const float*)d_in[8];
  const float* Wfc2 = (const float*)d_in[9];
  const float* bfc2 = (const float*)d_in[10];

  // 32768 elements / 16 per wave / 4 waves per block = 512 blocks
  lstm_fused<<<dim3(512), dim3(256), 0, stream>>>(
      x, W1, U1, b1, W2, U2, b2, Wfc1, bfc1, Wfc2, bfc2, (float*)d_out);
}